// Round 9
// baseline (31.726 us; speedup 1.0000x reference)
//
#include <hip/hip_runtime.h>
#include <hip/hip_bf16.h>

#define LN_EPS 1e-5f
#define TSB 40                 // LDS tile row stride in bf16 (80B, 16B-aligned)
#define TILEB (32 * TSB)       // shorts per tile
#define MAGIC 0x5A5A7E1Du

typedef __attribute__((ext_vector_type(8))) short bf16x8;
typedef __attribute__((ext_vector_type(16))) float f32x16;

__device__ __forceinline__ short bf16b(float f) {
  return __builtin_bit_cast(short, __float2bfloat16(f));
}

__device__ __forceinline__ void wave_reduce2(float& s1, float& s2) {
  #pragma unroll
  for (int off = 32; off; off >>= 1) {
    s1 += __shfl_xor(s1, off);
    s2 += __shfl_xor(s2, off);
  }
}

// A-frag/B-frag read from a row-major-[32][TSB] LDS tile.
// Normal tile -> A-operand (lane m holds A[m][k]); transposed tile -> B-operand.
__device__ __forceinline__ bf16x8 frag_ld(const short* t, int l, int k0) {
  return *(const bf16x8*)&t[(l & 31) * TSB + ((l >> 5) << 3) + k0];
}

__device__ __forceinline__ int cd_row(int r, int l) {
  return (r & 3) + 8 * (r >> 2) + 4 * (l >> 5);   // verified C/D mapping
}

__device__ __forceinline__ void cd_store(short* t, int l, const f32x16 d,
                                         bool transp) {
  const int col = l & 31;
  if (transp) {
    #pragma unroll
    for (int r = 0; r < 16; ++r) t[col * TSB + cd_row(r, l)] = bf16b(d[r]);
  } else {
    #pragma unroll
    for (int r = 0; r < 16; ++r) t[cd_row(r, l) * TSB + col] = bf16b(d[r]);
  }
}

struct NodeParams {
  bf16x8 w0, w1;        // Ww^T B-fragments (k0=0,16)
  float wb;             // Wb[col]
  float ga[16], be[16]; // gamma/beta at this lane's 16 C/D positions
};

__device__ __forceinline__ NodeParams load_params(const float* __restrict__ Ww,
    const float* __restrict__ Wb, const float* __restrict__ gamma,
    const float* __restrict__ beta, int l) {
  NodeParams P;
  const int n = l & 31, kh = (l >> 5) * 8;
  float w[8];
  *(float4*)&w[0] = *(const float4*)&Ww[n * 32 + kh];
  *(float4*)&w[4] = *(const float4*)&Ww[n * 32 + kh + 4];
  #pragma unroll
  for (int i = 0; i < 8; ++i) P.w0[i] = bf16b(w[i]);
  *(float4*)&w[0] = *(const float4*)&Ww[n * 32 + kh + 16];
  *(float4*)&w[4] = *(const float4*)&Ww[n * 32 + kh + 20];
  #pragma unroll
  for (int i = 0; i < 8; ++i) P.w1[i] = bf16b(w[i]);
  P.wb = Wb[n];
  #pragma unroll
  for (int r = 0; r < 16; ++r) {
    const int idx = cd_row(r, l) * 32 + n;
    P.ga[r] = gamma[idx];
    P.be[r] = beta[idx];
  }
  return P;
}

__device__ __forceinline__ f32x16 mm32(const short* A, const short* B, int l) {
  f32x16 acc = {};
  acc = __builtin_amdgcn_mfma_f32_32x32x16_bf16(frag_ld(A, l, 0),
                                                frag_ld(B, l, 0), acc, 0, 0, 0);
  acc = __builtin_amdgcn_mfma_f32_32x32x16_bf16(frag_ld(A, l, 16),
                                                frag_ld(B, l, 16), acc, 0, 0, 0);
  return acc;
}

// Full tree node on ONE wave. A = left child (normal), Bt = right child
// (transposed), Ct = emb C (transposed). T1 scratch -> A slot, T2 -> Bt slot
// (same-wave in-order LDS). Output h: fp32 to fout (root) or bf16 to dst.
__device__ __forceinline__ void node_mfma(short* A, short* Bt, const short* Ct,
                                          const NodeParams& P, int l,
                                          short* dst, bool transpOut,
                                          float* fout) {
  f32x16 t1 = mm32(A, Bt, l);
  cd_store(A, l, t1, false);            // T1 (normal) into A slot
  f32x16 t2 = mm32(A, Ct, l);
  cd_store(Bt, l, t2, false);           // T2 (normal) into Bt slot
  f32x16 x = {};
  x = __builtin_amdgcn_mfma_f32_32x32x16_bf16(frag_ld(Bt, l, 0), P.w0, x, 0, 0, 0);
  x = __builtin_amdgcn_mfma_f32_32x32x16_bf16(frag_ld(Bt, l, 16), P.w1, x, 0, 0, 0);
  float s1 = 0.f, s2 = 0.f;
  #pragma unroll
  for (int r = 0; r < 16; ++r) {
    x[r] += P.wb;
    s1 += x[r];
    s2 += x[r] * x[r];
  }
  wave_reduce2(s1, s2);
  const float mu = s1 * (1.f / 1024.f);
  const float rs = rsqrtf(s2 * (1.f / 1024.f) - mu * mu + LN_EPS);
  #pragma unroll
  for (int r = 0; r < 16; ++r)
    x[r] = fmaxf((x[r] - mu) * rs * P.ga[r] + P.be[r], 0.f);
  if (fout) {
    #pragma unroll
    for (int r = 0; r < 16; ++r) fout[cd_row(r, l) * 32 + (l & 31)] = x[r];
  } else {
    cd_store(dst, l, x, transpOut);
  }
}

// fp32 global tile [32][32] -> LDS bf16, normal or transposed; one wave
__device__ __forceinline__ void stage_f32(short* dst,
                                          const float* __restrict__ src, int l,
                                          bool transp) {
  float v[16];
  #pragma unroll
  for (int q = 0; q < 4; ++q)
    *(float4*)&v[q * 4] = *(const float4*)&src[l * 16 + q * 4];
  const int row = l >> 1, c0 = (l & 1) * 16;
  if (transp) {
    #pragma unroll
    for (int i = 0; i < 16; ++i) dst[(c0 + i) * TSB + row] = bf16b(v[i]);
  } else {
    #pragma unroll
    for (int i = 0; i < 8; ++i) {
      unsigned lo = (unsigned short)bf16b(v[2 * i]);
      unsigned hi = (unsigned short)bf16b(v[2 * i + 1]);
      ((unsigned*)dst)[row * (TSB / 2) + (c0 >> 1) + i] = lo | (hi << 16);
    }
  }
}

// 16 bf16 values (lane l covers shorts 16l..16l+15) -> LDS tile, parity layout
__device__ __forceinline__ void lds_put16(short* dst, const short v[16], int l,
                                          bool transp) {
  const int row = l >> 1, c0 = (l & 1) * 16;
  if (transp) {
    #pragma unroll
    for (int i = 0; i < 16; ++i) dst[(c0 + i) * TSB + row] = v[i];
  } else {
    #pragma unroll
    for (int i = 0; i < 8; ++i) {
      unsigned lo = (unsigned short)v[2 * i];
      unsigned hi = (unsigned short)v[2 * i + 1];
      ((unsigned*)dst)[row * (TSB / 2) + (c0 >> 1) + i] = lo | (hi << 16);
    }
  }
}

// coherent (agent-scope) tile fetch: global compact bf16 -> LDS
__device__ __forceinline__ void fetch_tile(short* dstLds,
                                           const unsigned* __restrict__ src,
                                           int l, bool transp) {
  short v[16];
  #pragma unroll
  for (int i = 0; i < 8; ++i) {
    unsigned x = __hip_atomic_load(src + l * 8 + i, __ATOMIC_RELAXED,
                                   __HIP_MEMORY_SCOPE_AGENT);
    v[2 * i] = (short)(x & 0xFFFFu);
    v[2 * i + 1] = (short)(x >> 16);
  }
  lds_put16(dstLds, v, l, transp);
}

// coherent tile emit: LDS normal tile -> global compact bf16 (512 u32)
__device__ __forceinline__ void emit_tile(unsigned* __restrict__ dst,
                                          const short* t, int u) {
  #pragma unroll
  for (int q = 0; q < 2; ++q) {
    const int w = 2 * u + q;
    const int row = w >> 4, cp = w & 15;
    unsigned v = *(const unsigned*)&t[row * TSB + cp * 2];
    __hip_atomic_store(dst + w, v, __ATOMIC_RELAXED, __HIP_MEMORY_SCOPE_AGENT);
  }
}

__device__ __forceinline__ void flag_set(unsigned* f) {
  __hip_atomic_store(f, MAGIC, __ATOMIC_RELAXED, __HIP_MEMORY_SCOPE_AGENT);
}

__device__ __forceinline__ void flag_wait(const unsigned* f) {
  while (__hip_atomic_load(f, __ATOMIC_RELAXED, __HIP_MEMORY_SCOPE_AGENT) !=
         MAGIC)
    __builtin_amdgcn_s_sleep(1);
  asm volatile("" ::: "memory");
}

// leaf: load fp32 tile, LN+ReLU in-wave, write bf16 with parity layout
__device__ __forceinline__ void leaf_ln(short* dst, const float* __restrict__ src,
                                        const float* __restrict__ gamma,
                                        const float* __restrict__ beta, int l,
                                        bool transp) {
  float v[16], ga[16], be[16];
  #pragma unroll
  for (int q = 0; q < 4; ++q) {
    *(float4*)&v[q * 4] = *(const float4*)&src[l * 16 + q * 4];
    *(float4*)&ga[q * 4] = *(const float4*)&gamma[l * 16 + q * 4];
    *(float4*)&be[q * 4] = *(const float4*)&beta[l * 16 + q * 4];
  }
  float s1 = 0.f, s2 = 0.f;
  #pragma unroll
  for (int i = 0; i < 16; ++i) { s1 += v[i]; s2 += v[i] * v[i]; }
  wave_reduce2(s1, s2);
  const float mu = s1 * (1.f / 1024.f);
  const float rs = rsqrtf(s2 * (1.f / 1024.f) - mu * mu + LN_EPS);
  short o[16];
  #pragma unroll
  for (int i = 0; i < 16; ++i)
    o[i] = bf16b(fmaxf((v[i] - mu) * rs * ga[i] + be[i], 0.f));
  lds_put16(dst, o, l, transp);
}

// Three levels (4 -> 2 -> 1 nodes) from hin (8 flagged tiles) to hout+flag.
__device__ __forceinline__ void phase3(
    int blk, int u, int wv, int l, short* pool, const NodeParams& P,
    const int* __restrict__ wid, const float* __restrict__ emb,
    const unsigned* __restrict__ hinu, const unsigned* __restrict__ finf,
    unsigned* __restrict__ houtu, unsigned* __restrict__ foutf,
    int b0, int b1, int b2) {
  // emb C tiles first (independent of producers): L-A -> 8..11, L-B -> 12,13, L-C -> 14
  stage_f32(pool + (8 + wv) * TILEB,
            emb + (size_t)wid[b0 + 4 * blk + wv] * 1024, l, true);
  if (wv < 2)
    stage_f32(pool + (12 + wv) * TILEB,
              emb + (size_t)wid[b1 + 2 * blk + wv] * 1024, l, true);
  else if (wv == 2)
    stage_f32(pool + 14 * TILEB, emb + (size_t)wid[b2 + blk] * 1024, l, true);
  if (u < 8) flag_wait(finf + 8 * blk + u);
  __syncthreads();
  // children: wave w -> tiles 2w (left, normal), 2w+1 (right, transposed)
  fetch_tile(pool + 2 * wv * TILEB, hinu + (size_t)(8 * blk + 2 * wv) * 512, l,
             false);
  fetch_tile(pool + (2 * wv + 1) * TILEB,
             hinu + (size_t)(8 * blk + 2 * wv + 1) * 512, l, true);
  __syncthreads();
  // level A: 4 nodes, one per wave; out -> C slot, parity by node index
  node_mfma(pool + 2 * wv * TILEB, pool + (2 * wv + 1) * TILEB,
            pool + (8 + wv) * TILEB, P, l, pool + (8 + wv) * TILEB,
            (wv & 1) != 0, nullptr);
  __syncthreads();
  // level B: 2 nodes on waves 0,1
  if (wv < 2)
    node_mfma(pool + (8 + 2 * wv) * TILEB, pool + (9 + 2 * wv) * TILEB,
              pool + (12 + wv) * TILEB, P, l, pool + (12 + wv) * TILEB,
              (wv & 1) != 0, nullptr);
  __syncthreads();
  // level C: 1 node on wave 0, out normal -> slot 14
  if (wv == 0)
    node_mfma(pool + 12 * TILEB, pool + 13 * TILEB, pool + 14 * TILEB, P, l,
              pool + 14 * TILEB, false, nullptr);
  __syncthreads();
  emit_tile(houtu + (size_t)blk * 512, pool + 14 * TILEB, u);
  asm volatile("s_waitcnt vmcnt(0)" ::: "memory");
  __syncthreads();
  if (u == 0) flag_set(foutf + blk);
}

// ---- the whole tree, one kernel, 256 blocks x 256 thr ----
__global__ __launch_bounds__(256) void k_tree(
    const int* __restrict__ wid, const float* __restrict__ emb,
    const float* __restrict__ Ww, const float* __restrict__ Wb,
    const float* __restrict__ gamma, const float* __restrict__ beta,
    const float* __restrict__ Pw, const float* __restrict__ Pb,
    const int* __restrict__ label,
    unsigned* __restrict__ h8u, unsigned* __restrict__ h5u,
    unsigned* __restrict__ h2u, unsigned* __restrict__ h8f,
    unsigned* __restrict__ h5f, unsigned* __restrict__ h2f,
    float* __restrict__ out) {
  __shared__ __align__(16) short pool[15 * TILEB];
  __shared__ float rootf[1024];
  __shared__ float lred[10];
  const int u = threadIdx.x, blk = blockIdx.x;
  const int wv = u >> 6, l = u & 63;
  NodeParams P = load_params(Ww, Wb, gamma, beta, l);

  // ---- bottom: 4 leaves + 2x L9 + 1x L8 (every block) ----
  {
    // C tiles (transposed): L9a->4, L9b->5, L8->6
    if (wv == 0)
      stage_f32(pool + 4 * TILEB, emb + (size_t)wid[511 + 2 * blk] * 1024, l, true);
    else if (wv == 1)
      stage_f32(pool + 5 * TILEB, emb + (size_t)wid[512 + 2 * blk] * 1024, l, true);
    else if (wv == 2)
      stage_f32(pool + 6 * TILEB, emb + (size_t)wid[255 + blk] * 1024, l, true);
    // leaves: one per wave -> slots 0..3; odd position = right = transposed
    leaf_ln(pool + wv * TILEB, emb + (size_t)wid[1023 + 4 * blk + wv] * 1024,
            gamma, beta, l, (wv & 1) != 0);
    __syncthreads();
    // L9: waves 0,1. Node m children = leaves 2m (slot 2m, normal A) and
    // 2m+1 (slot 2m+1, transposed B); C/out slot 4+m; right node out transp.
    if (wv < 2)
      node_mfma(pool + 2 * wv * TILEB, pool + (2 * wv + 1) * TILEB,
                pool + (4 + wv) * TILEB, P, l, pool + (4 + wv) * TILEB,
                wv == 1, nullptr);
    __syncthreads();
    // L8: wave 0: children 4,5, C 6 -> normal out in 6
    if (wv == 0)
      node_mfma(pool + 4 * TILEB, pool + 5 * TILEB, pool + 6 * TILEB, P, l,
                pool + 6 * TILEB, false, nullptr);
    __syncthreads();
    emit_tile(h8u + (size_t)blk * 512, pool + 6 * TILEB, u);
    asm volatile("s_waitcnt vmcnt(0)" ::: "memory");
    __syncthreads();
    if (u == 0) flag_set(h8f + blk);
  }

  if (blk >= 32) return;
  // ---- P2: L7, L6, L5 on blocks 0..31 ----
  phase3(blk, u, wv, l, pool, P, wid, emb, h8u, h8f, h5u, h5f, 127, 63, 31);

  if (blk >= 4) return;
  // ---- P3: L4, L3, L2 on blocks 0..3 ----
  phase3(blk, u, wv, l, pool, P, wid, emb, h5u, h5f, h2u, h2f, 15, 7, 3);

  if (blk >= 1) return;
  // ---- P4: L1, L0 + head on block 0 ----
  {
    // C tiles: L1a=wid[1]->4, L1b=wid[2]->5, L0=wid[0]->6 (transposed)
    if (wv == 0) stage_f32(pool + 4 * TILEB, emb + (size_t)wid[1] * 1024, l, true);
    else if (wv == 1) stage_f32(pool + 5 * TILEB, emb + (size_t)wid[2] * 1024, l, true);
    else if (wv == 2) stage_f32(pool + 6 * TILEB, emb + (size_t)wid[0] * 1024, l, true);
    if (u < 4) flag_wait(h2f + u);
    __syncthreads();
    // children h2[0..3] -> slots 0..3 (odd = right = transposed)
    fetch_tile(pool + wv * TILEB, h2u + (size_t)wv * 512, l, (wv & 1) != 0);
    __syncthreads();
    // L1: waves 0,1
    if (wv < 2)
      node_mfma(pool + 2 * wv * TILEB, pool + (2 * wv + 1) * TILEB,
                pool + (4 + wv) * TILEB, P, l, pool + (4 + wv) * TILEB, wv == 1,
                nullptr);
    __syncthreads();
    // L0 -> fp32 root
    if (wv == 0)
      node_mfma(pool + 4 * TILEB, pool + 5 * TILEB, pool + 6 * TILEB, P, l,
                nullptr, false, rootf);
    __syncthreads();
    // head: wave wv handles classes c = wv + 4q
    #pragma unroll
    for (int q = 0; q < 3; ++q) {
      const int c = wv + 4 * q;
      if (c < 10) {
        float p = 0.f;
        #pragma unroll
        for (int t = 0; t < 4; ++t) {
          float4 r4 = *(const float4*)&rootf[l * 16 + t * 4];
          float4 w4 = *(const float4*)&Pw[c * 1024 + l * 16 + t * 4];
          p += r4.x * w4.x + r4.y * w4.y + r4.z * w4.z + r4.w * w4.w;
        }
        #pragma unroll
        for (int off = 32; off; off >>= 1) p += __shfl_xor(p, off);
        if (l == 0) lred[c] = p + Pb[c];
      }
    }
    __syncthreads();
    if (u == 0) {
      float mmax = lred[0];
      int am = 0;
      #pragma unroll
      for (int c = 1; c < 10; ++c)
        if (lred[c] > mmax) { mmax = lred[c]; am = c; }
      float sum = 0.f;
      #pragma unroll
      for (int c = 0; c < 10; ++c) sum += expf(lred[c] - mmax);
      const float loss = -(lred[label[0]] - mmax - logf(sum));
      out[0] = (float)am;
      out[1] = loss;
    }
  }
}

extern "C" void kernel_launch(void* const* d_in, const int* in_sizes, int n_in,
                              void* d_out, int out_size, void* d_ws, size_t ws_size,
                              hipStream_t stream) {
  const int* wid = (const int*)d_in[0];
  const int* label = (const int*)d_in[1];
  const float* emb = (const float*)d_in[2];
  const float* Ww = (const float*)d_in[3];
  const float* Wb = (const float*)d_in[4];
  const float* g = (const float*)d_in[5];
  const float* b = (const float*)d_in[6];
  const float* Pw = (const float*)d_in[7];
  const float* Pb = (const float*)d_in[8];
  float* out = (float*)d_out;

  // workspace layout (u32 views of compact bf16 tiles, 512 u32 each)
  unsigned* h8u = (unsigned*)d_ws;          // 256 tiles
  unsigned* h5u = h8u + 256 * 512;          // 32 tiles
  unsigned* h2u = h5u + 32 * 512;           // 4 tiles
  unsigned* h8f = h2u + 4 * 512;            // 256 flags
  unsigned* h5f = h8f + 256;                // 32 flags
  unsigned* h2f = h5f + 32;                 // 4 flags

  k_tree<<<256, 256, 0, stream>>>(wid, emb, Ww, Wb, g, b, Pw, Pb, label,
                                  h8u, h5u, h2u, h8f, h5f, h2f, out);
}